// Round 6
// baseline (335.634 us; speedup 1.0000x reference)
//
#include <hip/hip_runtime.h>

// Problem constants
#define B_SZ 65536
#define NH   100

typedef __bf16 bf16_t;
typedef __bf16 bf16x2 __attribute__((ext_vector_type(2)));
typedef __bf16 bf16x8 __attribute__((ext_vector_type(8)));
typedef float  f32x4  __attribute__((ext_vector_type(4)));
typedef unsigned u32x2 __attribute__((ext_vector_type(2)));

// ---- d_ws layout ----
// bf16 region: A-fragment (weight-transposed) tiles for mfma_f32_16x16x32_bf16.
// frag (mt,kc): lane L=(Q=L>>4,c=L&15) holds A[m=mt*16+c][k=kc*32+Q*8+j], j=0..7.
#define SZ_W2 14336            // 7 m-tiles * 4 kc * 512
#define SZ_W3 8192             // 4 m-tiles * 4 kc * 512
#define SZ_W1 7168             // 7 m-tiles * 2 kc * 512 (per net per z-block)
#define OFF_W3   28672         // elems; after W2S,W2T
#define OFF_W1   45056         // elems; block b: S at +b*2*SZ_W1, T at +SZ_W1
#define WS_TOTAL 145408        // bf16 elems (290816 bytes)
// float region at ws+WS_TOTAL: [b2S 112][b2T 112][b3S 64][b3T 64][b1S 112][b1T 112]

__global__ void prep_weights(const float* __restrict__ sW1, const float* __restrict__ sW2,
                             const float* __restrict__ sW3, const float* __restrict__ tW1,
                             const float* __restrict__ tW2, const float* __restrict__ tW3,
                             bf16_t* __restrict__ ws) {
  int idx = blockIdx.x * 256 + threadIdx.x;
  if (idx >= WS_TOTAL) return;
  float v = 0.f;
  if (idx < 2 * SZ_W2) {                    // W2^T: A[m=out][k=in], 112x128
    const float* W = (idx < SZ_W2) ? sW2 : tW2;
    int l = (idx < SZ_W2) ? idx : idx - SZ_W2;
    int j = l & 7, ln = (l >> 3) & 63, kc = (l >> 9) & 3, mt = l >> 11;   // mt 0..6
    int k = kc * 32 + (ln >> 4) * 8 + j;    // in-hidden
    int m = mt * 16 + (ln & 15);            // out-hidden
    v = (k < NH && m < NH) ? W[k * NH + m] : 0.f;
  } else if (idx < OFF_W1) {                // W3^T: A[m=out 64][k=in], 64x128
    int l = idx - OFF_W3;
    const float* W = (l < SZ_W3) ? sW3 : tW3;
    l &= (SZ_W3 - 1);
    int j = l & 7, ln = (l >> 3) & 63, kc = (l >> 9) & 3, mt = l >> 11;   // mt 0..3
    int k = kc * 32 + (ln >> 4) * 8 + j;
    int m = mt * 16 + (ln & 15);
    v = (k < NH) ? W[k * 64 + m] : 0.f;
  } else {                                  // W1^T blocks 0..6: A[m=out 112][k=z 64]
    int l = idx - OFF_W1;
    int b = l / (2 * SZ_W1);
    int r2 = l - b * 2 * SZ_W1;
    const float* W = (r2 < SZ_W1) ? sW1 : tW1;
    int w = (r2 < SZ_W1) ? r2 : r2 - SZ_W1;
    int j = w & 7, ln = (w >> 3) & 63, kc = (w >> 9) & 1, mt = w >> 10;   // mt 0..6
    int k = kc * 32 + (ln >> 4) * 8 + j;    // 0..63
    int m = mt * 16 + (ln & 15);
    v = (m < NH) ? W[(b * 64 + k) * NH + m] : 0.f;
  }
  ws[idx] = (bf16_t)v;
}

__global__ void prep_bias(const float* __restrict__ sb1, const float* __restrict__ sb2,
                          const float* __restrict__ sb3, const float* __restrict__ tb1,
                          const float* __restrict__ tb2, const float* __restrict__ tb3,
                          float* __restrict__ fb) {
  int t = threadIdx.x;                      // single block, 576 threads
  if (t < 112)       fb[t] = (t < NH) ? sb2[t] : 0.f;
  else if (t < 224)  fb[t] = (t - 112 < NH) ? tb2[t - 112] : 0.f;
  else if (t < 288)  fb[t] = sb3[t - 224];
  else if (t < 352)  fb[t] = tb3[t - 288];
  else if (t < 464)  fb[t] = (t - 352 < NH) ? sb1[t - 352] : 0.f;
  else if (t < 576)  fb[t] = (t - 464 < NH) ? tb1[t - 464] : 0.f;
}

// async global->LDS 16B/lane: gptr per-lane, lptr wave-uniform base (+lane*16 implicit)
__device__ __forceinline__ void gload_lds16(const void* gptr, void* lptr) {
  __builtin_amdgcn_global_load_lds(
      (const __attribute__((address_space(1))) unsigned int*)gptr,
      (__attribute__((address_space(3))) unsigned int*)lptr, 16, 0, 0);
}

__device__ __forceinline__ unsigned pk2(float a, float b) {
  bf16x2 t = {(bf16_t)a, (bf16_t)b};
  return __builtin_bit_cast(unsigned, t);
}

// B-frag build via gfx950 permlane swaps (VALU, no LDS traffic, zero bank conflicts).
// permlane32_swap = axis transpose (operand<->laneb5); permlane16_swap = (operand<->laneb4).
// Net for plswap(lo,hi): value (tile t, srclane bits s1,s0) lands at
// (operand=s0, lane b5=t, b4=s1) -> exactly the mfma B-frag k-layout.
// IMPLEMENTATION NOTE (round 2/4 failures): a raw `asm` version of these swaps
// miscomputes under some schedules (DPP-family wait-state hazard; compiler
// can't insert hazard nops inside opaque asm). Use the BUILTINS (round-5
// verified) so the backend owns hazard handling and register allocation.
#if __has_builtin(__builtin_amdgcn_permlane32_swap) && __has_builtin(__builtin_amdgcn_permlane16_swap)
__device__ __forceinline__ void plswap(unsigned &x, unsigned &y) {
  u32x2 a = __builtin_amdgcn_permlane32_swap(x, y, false, false);
  u32x2 b = __builtin_amdgcn_permlane16_swap(a[0], a[1], false, false);
  x = b[0]; y = b[1];
}
#else
__device__ __forceinline__ void plswap(unsigned &x, unsigned &y) {
  unsigned xo, yo;
  asm volatile("v_mov_b32 %0, %2\n\t"
               "v_mov_b32 %1, %3\n\t"
               "s_nop 1\n\t"
               "v_permlane32_swap_b32 %0, %1\n\t"
               "s_nop 1\n\t"
               "v_permlane16_swap_b32 %0, %1"
               : "=&v"(xo), "=&v"(yo) : "v"(x), "v"(y));
  x = xo; y = yo;
}
#endif

__device__ __forceinline__ bf16x8 build_bfrag(unsigned lo0, unsigned lo1,
                                              unsigned hi0, unsigned hi1) {
  plswap(lo0, hi0);
  plswap(lo1, hi1);
  union { unsigned u[4]; bf16x8 v; } r;
  r.u[0] = lo0; r.u[1] = lo1; r.u[2] = hi0; r.u[3] = hi1;
  return r.v;
}

struct __align__(16) SMem {
  bf16_t w2[2 * SZ_W2];       // 57344 B
  bf16_t w3[2 * SZ_W3];       // 32768 B
  bf16_t w1[2][2 * SZ_W1];    // double-buffered current z-block (S,T)  57344 B
  float  bias[512];           // b2S,b2T,b3S,b3T (+unused tail)          2048 B
};                            // 149504 B -> 1 block/CU, 16 waves (4/SIMD)

// 256 blocks x 1024 threads (16 waves); wave owns 16 batch COLUMNS (1 n-tile).
// Occupancy lever (round 6): same total work and LDS as the 8-wave version,
// but 4 waves/SIMD instead of 2 -> dependent VALU/permlane/MFMA chains from
// one wave overlap with three others. Per-wave state halves (~100 VGPR).
// All GEMMs as Y = W^T @ X: A=weights (LDS frags, double-buffered W1 prefetch),
// B=activations built in-reg via permlane swaps. 1 barrier/step.
__global__ __launch_bounds__(1024, 4) void flow_kernel(
    const float* __restrict__ e,
    const bf16_t* __restrict__ wf,
    const float* __restrict__ fb,
    float* __restrict__ out) {
  __shared__ SMem sm;

  const int tid  = threadIdx.x;
  const int wave = tid >> 6;           // 0..15
  const int lane = tid & 63;
  const int c    = lane & 15;          // batch col within n-tile
  const int Q    = lane >> 4;
  const int rowBase = blockIdx.x * 256 + wave * 16;

  // ---- initial stage: W2,W3 (90112B) + W1 blk0 -> buf0 (28672B) + bias (2KB)
  {
    const char* g = (const char*)wf;
    char* l = (char*)&sm;
    const char* gb = (const char*)fb;
    #pragma unroll
    for (int t = 0; t < 8; ++t) {
      const int ch = t * 16 + wave;
      if (ch < 116)      gload_lds16(g + ch * 1024 + lane * 16, l + ch * 1024);
      else if (ch < 118) gload_lds16(gb + (ch - 116) * 1024 + lane * 16,
                                     (char*)sm.bias + (ch - 116) * 1024);
    }
  }

  // persistent layer-1 pre-activations (+b1), C-layout [7 tiles]
  f32x4 acc1S[7], acc1T[7];
  #pragma unroll
  for (int th = 0; th < 7; ++th) {
    acc1S[th] = *(const f32x4*)(fb + 352 + th * 16 + Q * 4);
    acc1T[th] = *(const f32x4*)(fb + 464 + th * 16 + Q * 4);
  }
  float ldacc = 0.f;

  __syncthreads();   // weights + blk0 + bias resident

  const float* lb2S = sm.bias;
  const float* lb2T = sm.bias + 112;
  const float* lb3S = sm.bias + 224;
  const float* lb3T = sm.bias + 288;

  // acc1 -> relu/pack -> (permlane B-frag) -> L2 -> relu/pack -> L3 -> acc3
  auto run_net = [&](const f32x4 (&acc1)[7], const bf16_t* __restrict__ w2f,
                     const bf16_t* __restrict__ w3f, const float* __restrict__ lb2,
                     const float* __restrict__ lb3, f32x4 (&acc3)[4]) {
    unsigned pk[7][2];
    #pragma unroll
    for (int th = 0; th < 7; ++th) {
      pk[th][0] = pk2(fmaxf(acc1[th][0], 0.f), fmaxf(acc1[th][1], 0.f));
      pk[th][1] = pk2(fmaxf(acc1[th][2], 0.f), fmaxf(acc1[th][3], 0.f));
    }
    f32x4 acc2[7];
    #pragma unroll
    for (int th = 0; th < 7; ++th)
      acc2[th] = *(const f32x4*)(lb2 + th * 16 + Q * 4);
    #pragma unroll
    for (int kc = 0; kc < 4; ++kc) {
      // kc==3: k=96..127; only k=96..99 real (tile 6, sourced by LO input).
      // hi input feeds only k>=112 (zero-A) -> tile 5 as a distinct dummy.
      const int tlo = kc * 2, thi = (kc * 2 + 1 > 6) ? 5 : kc * 2 + 1;
      const bf16x8 b0 = build_bfrag(pk[tlo][0], pk[tlo][1], pk[thi][0], pk[thi][1]);
      #pragma unroll
      for (int th = 0; th < 7; ++th) {
        const bf16x8 A = *(const bf16x8*)(w2f + ((th * 4 + kc) * 64 + lane) * 8);
        acc2[th] = __builtin_amdgcn_mfma_f32_16x16x32_bf16(A, b0, acc2[th], 0, 0, 0);
      }
    }
    // layer 3
    #pragma unroll
    for (int th = 0; th < 7; ++th) {
      pk[th][0] = pk2(fmaxf(acc2[th][0], 0.f), fmaxf(acc2[th][1], 0.f));
      pk[th][1] = pk2(fmaxf(acc2[th][2], 0.f), fmaxf(acc2[th][3], 0.f));
    }
    #pragma unroll
    for (int ot = 0; ot < 4; ++ot)
      acc3[ot] = *(const f32x4*)(lb3 + ot * 16 + Q * 4);
    #pragma unroll
    for (int kc = 0; kc < 4; ++kc) {
      const int tlo = kc * 2, thi = (kc * 2 + 1 > 6) ? 5 : kc * 2 + 1;
      const bf16x8 b0 = build_bfrag(pk[tlo][0], pk[tlo][1], pk[thi][0], pk[thi][1]);
      #pragma unroll
      for (int ot = 0; ot < 4; ++ot) {
        const bf16x8 A = *(const bf16x8*)(w3f + ((ot * 4 + kc) * 64 + lane) * 8);
        acc3[ot] = __builtin_amdgcn_mfma_f32_16x16x32_bf16(A, b0, acc3[ot], 0, 0, 0);
      }
    }
  };

  for (int i = 0; i < 8; ++i) {
    f32x4 acc3S[4], acc3T[4];
    run_net(acc1S, sm.w2,         sm.w3,         lb2S, lb3S, acc3S);
    run_net(acc1T, sm.w2 + SZ_W2, sm.w3 + SZ_W3, lb2T, lb3T, acc3T);

    // ---- epilogue: s,t=sigmoid (fast rcp); z=exp(s)*e+t (f32x4 rows); logdet ----
    unsigned zpk[4][2];
    #pragma unroll
    for (int ot = 0; ot < 4; ++ot) {
      const int off = (rowBase + c) * 512 + i * 64 + ot * 16 + Q * 4;
      const f32x4 ev = *(const f32x4*)(e + off);
      f32x4 zv;
      float ss = 0.f;
      #pragma unroll
      for (int r = 0; r < 4; ++r) {
        const float sv = __builtin_amdgcn_rcpf(1.f + __expf(-acc3S[ot][r]));
        const float tv = __builtin_amdgcn_rcpf(1.f + __expf(-acc3T[ot][r]));
        zv[r] = __expf(sv) * ev[r] + tv;
        ss += sv;
      }
      __builtin_nontemporal_store(zv, (f32x4*)(out + off));
      zpk[ot][0] = pk2(zv[0], zv[1]);
      zpk[ot][1] = pk2(zv[2], zv[3]);
      ldacc += ss;
    }

    // ---- incremental layer-1 update: acc1 += W1_i^T @ z_i ----
    if (i < 7) {
      __syncthreads();   // blk i resident in buf[i&1] (all waves' chunks drained)
      const bf16_t* __restrict__ w1b = sm.w1[i & 1];
      #pragma unroll
      for (int kc = 0; kc < 2; ++kc) {
        const bf16x8 b0 = build_bfrag(zpk[kc * 2][0], zpk[kc * 2][1],
                                      zpk[kc * 2 + 1][0], zpk[kc * 2 + 1][1]);
        #pragma unroll
        for (int th = 0; th < 7; ++th) {
          const bf16x8 AS = *(const bf16x8*)(w1b + ((th * 2 + kc) * 64 + lane) * 8);
          const bf16x8 AT = *(const bf16x8*)(w1b + SZ_W1 + ((th * 2 + kc) * 64 + lane) * 8);
          acc1S[th] = __builtin_amdgcn_mfma_f32_16x16x32_bf16(AS, b0, acc1S[th], 0, 0, 0);
          acc1T[th] = __builtin_amdgcn_mfma_f32_16x16x32_bf16(AT, b0, acc1T[th], 0, 0, 0);
        }
      }
      if (i < 6) {   // prefetch blk i+1 -> buf[(i+1)&1]; consumed after NEXT barrier
        const char* g = (const char*)wf + 90112 + (i + 1) * 28672;
        char* l = (char*)sm.w1[(i + 1) & 1];
        #pragma unroll
        for (int t = 0; t < 2; ++t) {
          const int ch = t * 16 + wave;
          if (ch < 28) gload_lds16(g + ch * 1024 + lane * 16, l + ch * 1024);
        }
      }
    }
  }

  // log_det: reduce over Q (lanes c, c+16, c+32, c+48); Q==0 lanes write
  {
    float v = ldacc;
    v += __shfl_xor(v, 16);
    v += __shfl_xor(v, 32);
    if (Q == 0) out[B_SZ * 512 + rowBase + c] = v;
  }
}

extern "C" void kernel_launch(void* const* d_in, const int* in_sizes, int n_in,
                              void* d_out, int out_size, void* d_ws, size_t ws_size,
                              hipStream_t stream) {
  (void)in_sizes; (void)n_in; (void)out_size; (void)ws_size;
  const float* e   = (const float*)d_in[0];
  // d_in[1] is C (fixed strict-upper-triangular structure; encoded in the algorithm)
  const float* sW1 = (const float*)d_in[2];
  const float* sb1 = (const float*)d_in[3];
  const float* sW2 = (const float*)d_in[4];
  const float* sb2 = (const float*)d_in[5];
  const float* sW3 = (const float*)d_in[6];
  const float* sb3 = (const float*)d_in[7];
  const float* tW1 = (const float*)d_in[8];
  const float* tb1 = (const float*)d_in[9];
  const float* tW2 = (const float*)d_in[10];
  const float* tb2 = (const float*)d_in[11];
  const float* tW3 = (const float*)d_in[12];
  const float* tb3 = (const float*)d_in[13];
  bf16_t* ws = (bf16_t*)d_ws;                  // needs ~287 KB
  float*  fb = (float*)(ws + WS_TOTAL);
  float* out = (float*)d_out;

  prep_weights<<<(WS_TOTAL + 255) / 256, 256, 0, stream>>>(sW1, sW2, sW3, tW1, tW2, tW3, ws);
  prep_bias<<<1, 576, 0, stream>>>(sb1, sb2, sb3, tb1, tb2, tb3, fb);
  flow_kernel<<<256, 1024, 0, stream>>>(e, ws, fb, out);
}

// Round 7
// 317.606 us; speedup vs baseline: 1.0568x; 1.0568x over previous
//
#include <hip/hip_runtime.h>

// Problem constants
#define B_SZ 65536
#define NH   100

typedef __bf16 bf16_t;
typedef __bf16 bf16x2 __attribute__((ext_vector_type(2)));
typedef __bf16 bf16x8 __attribute__((ext_vector_type(8)));
typedef float  f32x4  __attribute__((ext_vector_type(4)));
typedef unsigned u32x2 __attribute__((ext_vector_type(2)));

// ---- d_ws layout ----
// bf16 region: A-fragment (weight-transposed) tiles for mfma_f32_16x16x32_bf16.
// frag (mt,kc): lane L=(Q=L>>4,c=L&15) holds A[m=mt*16+c][k=kc*32+Q*8+j], j=0..7.
#define SZ_W2 14336            // 7 m-tiles * 4 kc * 512
#define SZ_W3 8192             // 4 m-tiles * 4 kc * 512
#define SZ_W1 7168             // 7 m-tiles * 2 kc * 512 (per net per z-block)
#define OFF_W3   28672         // elems; after W2S,W2T
#define OFF_W1   45056         // elems; block b: S at +b*2*SZ_W1, T at +SZ_W1
#define WS_TOTAL 145408        // bf16 elems (290816 bytes)
// float region at ws+WS_TOTAL: [b2S 112][b2T 112][b3S 64][b3T 64][b1S 112][b1T 112]

__global__ void prep_weights(const float* __restrict__ sW1, const float* __restrict__ sW2,
                             const float* __restrict__ sW3, const float* __restrict__ tW1,
                             const float* __restrict__ tW2, const float* __restrict__ tW3,
                             bf16_t* __restrict__ ws) {
  int idx = blockIdx.x * 256 + threadIdx.x;
  if (idx >= WS_TOTAL) return;
  float v = 0.f;
  if (idx < 2 * SZ_W2) {                    // W2^T: A[m=out][k=in], 112x128
    const float* W = (idx < SZ_W2) ? sW2 : tW2;
    int l = (idx < SZ_W2) ? idx : idx - SZ_W2;
    int j = l & 7, ln = (l >> 3) & 63, kc = (l >> 9) & 3, mt = l >> 11;   // mt 0..6
    int k = kc * 32 + (ln >> 4) * 8 + j;    // in-hidden
    int m = mt * 16 + (ln & 15);            // out-hidden
    v = (k < NH && m < NH) ? W[k * NH + m] : 0.f;
  } else if (idx < OFF_W1) {                // W3^T: A[m=out 64][k=in], 64x128
    int l = idx - OFF_W3;
    const float* W = (l < SZ_W3) ? sW3 : tW3;
    l &= (SZ_W3 - 1);
    int j = l & 7, ln = (l >> 3) & 63, kc = (l >> 9) & 3, mt = l >> 11;   // mt 0..3
    int k = kc * 32 + (ln >> 4) * 8 + j;
    int m = mt * 16 + (ln & 15);
    v = (k < NH) ? W[k * 64 + m] : 0.f;
  } else {                                  // W1^T blocks 0..6: A[m=out 112][k=z 64]
    int l = idx - OFF_W1;
    int b = l / (2 * SZ_W1);
    int r2 = l - b * 2 * SZ_W1;
    const float* W = (r2 < SZ_W1) ? sW1 : tW1;
    int w = (r2 < SZ_W1) ? r2 : r2 - SZ_W1;
    int j = w & 7, ln = (w >> 3) & 63, kc = (w >> 9) & 1, mt = w >> 10;   // mt 0..6
    int k = kc * 32 + (ln >> 4) * 8 + j;    // 0..63
    int m = mt * 16 + (ln & 15);
    v = (m < NH) ? W[(b * 64 + k) * NH + m] : 0.f;
  }
  ws[idx] = (bf16_t)v;
}

__global__ void prep_bias(const float* __restrict__ sb1, const float* __restrict__ sb2,
                          const float* __restrict__ sb3, const float* __restrict__ tb1,
                          const float* __restrict__ tb2, const float* __restrict__ tb3,
                          float* __restrict__ fb) {
  int t = threadIdx.x;                      // single block, 576 threads
  if (t < 112)       fb[t] = (t < NH) ? sb2[t] : 0.f;
  else if (t < 224)  fb[t] = (t - 112 < NH) ? tb2[t - 112] : 0.f;
  else if (t < 288)  fb[t] = sb3[t - 224];
  else if (t < 352)  fb[t] = tb3[t - 288];
  else if (t < 464)  fb[t] = (t - 352 < NH) ? sb1[t - 352] : 0.f;
  else if (t < 576)  fb[t] = (t - 464 < NH) ? tb1[t - 464] : 0.f;
}

// async global->LDS 16B/lane: gptr per-lane, lptr wave-uniform base (+lane*16 implicit)
__device__ __forceinline__ void gload_lds16(const void* gptr, void* lptr) {
  __builtin_amdgcn_global_load_lds(
      (const __attribute__((address_space(1))) unsigned int*)gptr,
      (__attribute__((address_space(3))) unsigned int*)lptr, 16, 0, 0);
}

__device__ __forceinline__ unsigned pk2(float a, float b) {
  bf16x2 t = {(bf16_t)a, (bf16_t)b};
  return __builtin_bit_cast(unsigned, t);
}

// B-frag build via gfx950 permlane swaps (VALU, no LDS traffic, zero bank conflicts).
// permlane32_swap = axis transpose (operand<->laneb5); permlane16_swap = (operand<->laneb4).
// Net for plswap(lo,hi): value (tile t, srclane bits s1,s0) lands at
// (operand=s0, lane b5=t, b4=s1) -> exactly the mfma B-frag k-layout.
// IMPLEMENTATION NOTE (round 2/4 failures): a raw `asm` version of these swaps
// miscomputes under some schedules (DPP-family wait-state hazard; compiler
// can't insert hazard nops inside opaque asm). Use the BUILTINS (round-5
// verified) so the backend owns hazard handling and register allocation.
#if __has_builtin(__builtin_amdgcn_permlane32_swap) && __has_builtin(__builtin_amdgcn_permlane16_swap)
__device__ __forceinline__ void plswap(unsigned &x, unsigned &y) {
  u32x2 a = __builtin_amdgcn_permlane32_swap(x, y, false, false);
  u32x2 b = __builtin_amdgcn_permlane16_swap(a[0], a[1], false, false);
  x = b[0]; y = b[1];
}
#else
__device__ __forceinline__ void plswap(unsigned &x, unsigned &y) {
  unsigned xo, yo;
  asm volatile("v_mov_b32 %0, %2\n\t"
               "v_mov_b32 %1, %3\n\t"
               "s_nop 1\n\t"
               "v_permlane32_swap_b32 %0, %1\n\t"
               "s_nop 1\n\t"
               "v_permlane16_swap_b32 %0, %1"
               : "=&v"(xo), "=&v"(yo) : "v"(x), "v"(y));
  x = xo; y = yo;
}
#endif

__device__ __forceinline__ bf16x8 build_bfrag(unsigned lo0, unsigned lo1,
                                              unsigned hi0, unsigned hi1) {
  plswap(lo0, hi0);
  plswap(lo1, hi1);
  union { unsigned u[4]; bf16x8 v; } r;
  r.u[0] = lo0; r.u[1] = lo1; r.u[2] = hi0; r.u[3] = hi1;
  return r.v;
}

struct __align__(16) SMem {
  bf16_t w2[2 * SZ_W2];       // 57344 B
  bf16_t w3[2 * SZ_W3];       // 32768 B
  bf16_t w1[2][2 * SZ_W1];    // double-buffered current z-block (S,T)  57344 B
  float  bias[512];           // b2S,b2T,b3S,b3T (+unused tail)          2048 B
};                            // 149504 B -> 1 block/CU, 8 waves (2/SIMD)

// 256 blocks x 512 threads; wave owns 32 batch COLUMNS (2 n-tiles).
// All GEMMs as Y = W^T @ X: A=weights (LDS frags, double-buffered W1 prefetch),
// B=activations built in-reg via permlane swaps. 1 barrier/step.
//
// REGISTER PRESSURE (round-7 fix): logical per-wave state ~215 VGPR (acc1 S+T
// 112 persistent + acc2 56 + pk 28 + temps). With plain __launch_bounds__ the
// backend heuristically squeezed to 128 VGPR (round 5) / 64 (round 6),
// spilling acc1 to scratch every step; at 16 waves the scratch overflowed the
// 4MB/XCD L2 into HBM (round 6: +100MB FETCH+WRITE, occupancy up but VALUBusy
// DOWN). amdgpu_waves_per_eu(2,2) pins occupancy at exactly 2 waves/SIMD
// (which the 149.5KB LDS forces anyway: 1 block/CU x 8 waves) so the
// allocator may use up to 256 VGPRs -> zero spills.
__global__ __launch_bounds__(512)
__attribute__((amdgpu_waves_per_eu(2, 2))) void flow_kernel(
    const float* __restrict__ e,
    const bf16_t* __restrict__ wf,
    const float* __restrict__ fb,
    float* __restrict__ out) {
  __shared__ SMem sm;

  const int tid  = threadIdx.x;
  const int wave = tid >> 6;
  const int lane = tid & 63;
  const int c    = lane & 15;          // batch col within n-tile
  const int Q    = lane >> 4;
  const int rowBase = blockIdx.x * 256 + wave * 32;

  // ---- initial stage: W2,W3 (90112B) + W1 blk0 -> buf0 (28672B) + bias (2KB)
  {
    const char* g = (const char*)wf;
    char* l = (char*)&sm;
    const char* gb = (const char*)fb;
    #pragma unroll
    for (int t = 0; t < 15; ++t) {
      const int ch = t * 8 + wave;
      if (ch < 116)      gload_lds16(g + ch * 1024 + lane * 16, l + ch * 1024);
      else if (ch < 118) gload_lds16(gb + (ch - 116) * 1024 + lane * 16,
                                     (char*)sm.bias + (ch - 116) * 1024);
    }
  }

  // persistent layer-1 pre-activations (+b1), C-layout [mt][7 tiles]
  f32x4 acc1S[2][7], acc1T[2][7];
  #pragma unroll
  for (int th = 0; th < 7; ++th) {
    const f32x4 vs = *(const f32x4*)(fb + 352 + th * 16 + Q * 4);
    const f32x4 vt = *(const f32x4*)(fb + 464 + th * 16 + Q * 4);
    acc1S[0][th] = vs; acc1S[1][th] = vs;
    acc1T[0][th] = vt; acc1T[1][th] = vt;
  }
  float ldacc[2] = {0.f, 0.f};

  __syncthreads();   // weights + blk0 + bias resident

  const float* lb2S = sm.bias;
  const float* lb2T = sm.bias + 112;
  const float* lb3S = sm.bias + 224;
  const float* lb3T = sm.bias + 288;

  // acc1 -> relu/pack -> (permlane B-frags) -> L2 -> relu/pack -> L3 -> acc3
  auto run_net = [&](const f32x4 (&acc1)[2][7], const bf16_t* __restrict__ w2f,
                     const bf16_t* __restrict__ w3f, const float* __restrict__ lb2,
                     const float* __restrict__ lb3, f32x4 (&acc3)[2][4]) {
    unsigned pk[2][7][2];
    #pragma unroll
    for (int mt = 0; mt < 2; ++mt)
      #pragma unroll
      for (int th = 0; th < 7; ++th) {
        pk[mt][th][0] = pk2(fmaxf(acc1[mt][th][0], 0.f), fmaxf(acc1[mt][th][1], 0.f));
        pk[mt][th][1] = pk2(fmaxf(acc1[mt][th][2], 0.f), fmaxf(acc1[mt][th][3], 0.f));
      }
    f32x4 acc2[2][7];
    #pragma unroll
    for (int th = 0; th < 7; ++th) {
      const f32x4 bv = *(const f32x4*)(lb2 + th * 16 + Q * 4);
      acc2[0][th] = bv; acc2[1][th] = bv;
    }
    #pragma unroll
    for (int kc = 0; kc < 4; ++kc) {
      // kc==3: k=96..127; only k=96..99 real (tile 6, sourced by LO input).
      // hi input feeds only k>=112 (zero-A) -> tile 5 as a distinct dummy.
      const int tlo = kc * 2, thi = (kc * 2 + 1 > 6) ? 5 : kc * 2 + 1;
      const bf16x8 b0 = build_bfrag(pk[0][tlo][0], pk[0][tlo][1], pk[0][thi][0], pk[0][thi][1]);
      const bf16x8 b1 = build_bfrag(pk[1][tlo][0], pk[1][tlo][1], pk[1][thi][0], pk[1][thi][1]);
      #pragma unroll
      for (int th = 0; th < 7; ++th) {
        const bf16x8 A = *(const bf16x8*)(w2f + ((th * 4 + kc) * 64 + lane) * 8);
        acc2[0][th] = __builtin_amdgcn_mfma_f32_16x16x32_bf16(A, b0, acc2[0][th], 0, 0, 0);
        acc2[1][th] = __builtin_amdgcn_mfma_f32_16x16x32_bf16(A, b1, acc2[1][th], 0, 0, 0);
      }
    }
    // layer 3
    #pragma unroll
    for (int mt = 0; mt < 2; ++mt)
      #pragma unroll
      for (int th = 0; th < 7; ++th) {
        pk[mt][th][0] = pk2(fmaxf(acc2[mt][th][0], 0.f), fmaxf(acc2[mt][th][1], 0.f));
        pk[mt][th][1] = pk2(fmaxf(acc2[mt][th][2], 0.f), fmaxf(acc2[mt][th][3], 0.f));
      }
    #pragma unroll
    for (int ot = 0; ot < 4; ++ot) {
      const f32x4 bv = *(const f32x4*)(lb3 + ot * 16 + Q * 4);
      acc3[0][ot] = bv; acc3[1][ot] = bv;
    }
    #pragma unroll
    for (int kc = 0; kc < 4; ++kc) {
      const int tlo = kc * 2, thi = (kc * 2 + 1 > 6) ? 5 : kc * 2 + 1;
      const bf16x8 b0 = build_bfrag(pk[0][tlo][0], pk[0][tlo][1], pk[0][thi][0], pk[0][thi][1]);
      const bf16x8 b1 = build_bfrag(pk[1][tlo][0], pk[1][tlo][1], pk[1][thi][0], pk[1][thi][1]);
      #pragma unroll
      for (int ot = 0; ot < 4; ++ot) {
        const bf16x8 A = *(const bf16x8*)(w3f + ((ot * 4 + kc) * 64 + lane) * 8);
        acc3[0][ot] = __builtin_amdgcn_mfma_f32_16x16x32_bf16(A, b0, acc3[0][ot], 0, 0, 0);
        acc3[1][ot] = __builtin_amdgcn_mfma_f32_16x16x32_bf16(A, b1, acc3[1][ot], 0, 0, 0);
      }
    }
  };

  for (int i = 0; i < 8; ++i) {
    f32x4 acc3S[2][4], acc3T[2][4];
    run_net(acc1S, sm.w2,         sm.w3,         lb2S, lb3S, acc3S);
    run_net(acc1T, sm.w2 + SZ_W2, sm.w3 + SZ_W3, lb2T, lb3T, acc3T);

    // ---- epilogue: s,t=sigmoid (fast rcp); z=exp(s)*e+t (f32x4 rows); logdet ----
    unsigned zpk[2][4][2];
    #pragma unroll
    for (int mt = 0; mt < 2; ++mt) {
      #pragma unroll
      for (int ot = 0; ot < 4; ++ot) {
        const int off = (rowBase + mt * 16 + c) * 512 + i * 64 + ot * 16 + Q * 4;
        const f32x4 ev = *(const f32x4*)(e + off);
        f32x4 zv;
        float ss = 0.f;
        #pragma unroll
        for (int r = 0; r < 4; ++r) {
          const float sv = __builtin_amdgcn_rcpf(1.f + __expf(-acc3S[mt][ot][r]));
          const float tv = __builtin_amdgcn_rcpf(1.f + __expf(-acc3T[mt][ot][r]));
          zv[r] = __expf(sv) * ev[r] + tv;
          ss += sv;
        }
        __builtin_nontemporal_store(zv, (f32x4*)(out + off));
        zpk[mt][ot][0] = pk2(zv[0], zv[1]);
        zpk[mt][ot][1] = pk2(zv[2], zv[3]);
        ldacc[mt] += ss;
      }
    }

    // ---- incremental layer-1 update: acc1 += W1_i^T @ z_i ----
    if (i < 7) {
      __syncthreads();   // blk i resident in buf[i&1] (all waves' chunks drained)
      const bf16_t* __restrict__ w1b = sm.w1[i & 1];
      #pragma unroll
      for (int kc = 0; kc < 2; ++kc) {
        const bf16x8 b0 = build_bfrag(zpk[0][kc * 2][0], zpk[0][kc * 2][1],
                                      zpk[0][kc * 2 + 1][0], zpk[0][kc * 2 + 1][1]);
        const bf16x8 b1 = build_bfrag(zpk[1][kc * 2][0], zpk[1][kc * 2][1],
                                      zpk[1][kc * 2 + 1][0], zpk[1][kc * 2 + 1][1]);
        #pragma unroll
        for (int th = 0; th < 7; ++th) {
          const bf16x8 AS = *(const bf16x8*)(w1b + ((th * 2 + kc) * 64 + lane) * 8);
          const bf16x8 AT = *(const bf16x8*)(w1b + SZ_W1 + ((th * 2 + kc) * 64 + lane) * 8);
          acc1S[0][th] = __builtin_amdgcn_mfma_f32_16x16x32_bf16(AS, b0, acc1S[0][th], 0, 0, 0);
          acc1S[1][th] = __builtin_amdgcn_mfma_f32_16x16x32_bf16(AS, b1, acc1S[1][th], 0, 0, 0);
          acc1T[0][th] = __builtin_amdgcn_mfma_f32_16x16x32_bf16(AT, b0, acc1T[0][th], 0, 0, 0);
          acc1T[1][th] = __builtin_amdgcn_mfma_f32_16x16x32_bf16(AT, b1, acc1T[1][th], 0, 0, 0);
        }
      }
      if (i < 6) {   // prefetch blk i+1 -> buf[(i+1)&1]; consumed after NEXT barrier
        const char* g = (const char*)wf + 90112 + (i + 1) * 28672;
        char* l = (char*)sm.w1[(i + 1) & 1];
        #pragma unroll
        for (int t = 0; t < 4; ++t) {
          const int ch = t * 8 + wave;
          if (ch < 28) gload_lds16(g + ch * 1024 + lane * 16, l + ch * 1024);
        }
      }
    }
  }

  // log_det: reduce over Q (lanes c, c+16, c+32, c+48); Q==0 lanes write
  #pragma unroll
  for (int mt = 0; mt < 2; ++mt) {
    float v = ldacc[mt];
    v += __shfl_xor(v, 16);
    v += __shfl_xor(v, 32);
    if (Q == 0) out[B_SZ * 512 + rowBase + mt * 16 + c] = v;
  }
}

extern "C" void kernel_launch(void* const* d_in, const int* in_sizes, int n_in,
                              void* d_out, int out_size, void* d_ws, size_t ws_size,
                              hipStream_t stream) {
  (void)in_sizes; (void)n_in; (void)out_size; (void)ws_size;
  const float* e   = (const float*)d_in[0];
  // d_in[1] is C (fixed strict-upper-triangular structure; encoded in the algorithm)
  const float* sW1 = (const float*)d_in[2];
  const float* sb1 = (const float*)d_in[3];
  const float* sW2 = (const float*)d_in[4];
  const float* sb2 = (const float*)d_in[5];
  const float* sW3 = (const float*)d_in[6];
  const float* sb3 = (const float*)d_in[7];
  const float* tW1 = (const float*)d_in[8];
  const float* tb1 = (const float*)d_in[9];
  const float* tW2 = (const float*)d_in[10];
  const float* tb2 = (const float*)d_in[11];
  const float* tW3 = (const float*)d_in[12];
  const float* tb3 = (const float*)d_in[13];
  bf16_t* ws = (bf16_t*)d_ws;                  // needs ~287 KB
  float*  fb = (float*)(ws + WS_TOTAL);
  float* out = (float*)d_out;

  prep_weights<<<(WS_TOTAL + 255) / 256, 256, 0, stream>>>(sW1, sW2, sW3, tW1, tW2, tW3, ws);
  prep_bias<<<1, 576, 0, stream>>>(sb1, sb2, sb3, tb1, tb2, tb3, fb);
  flow_kernel<<<256, 512, 0, stream>>>(e, ws, fb, out);
}